// Round 1
// baseline (501.745 us; speedup 1.0000x reference)
//
#include <hip/hip_runtime.h>
#include <hip/hip_bf16.h>
#include <cstdint>

// Problem constants (fixed by reference):
#define IDF 256
#define CDF 256
#define NL  128
#define HXW 4096
#define NB  32

// ws layout: [0..3] int mask-mode flag; [1024 ..] source array (32*256*128 f32 = 4MB)
// requires ws_size >= 4MB + 1KB.

__device__ __forceinline__ unsigned short f2bf(float f) {
  unsigned u = __float_as_uint(f);
  u += 0x7FFFu + ((u >> 16) & 1u);  // round-to-nearest-even
  return (unsigned short)(u >> 16);
}

// ---------------- mask dtype detection ----------------
// mask is bool in the reference; harness ABI may deliver int32, float32 or uint8.
// Classify by bit pattern of the first 1024 dwords (4KB — valid for all cases).
__global__ void detect_mask_kernel(const unsigned int* __restrict__ m, int* __restrict__ flag) {
  __shared__ int bad_int, bad_float;
  if (threadIdx.x == 0) { bad_int = 0; bad_float = 0; }
  __syncthreads();
  int bi = 0, bf = 0;
  for (int k = 0; k < 4; ++k) {
    unsigned int v = m[threadIdx.x * 4 + k];
    if (v > 1u) bi = 1;                     // int32 0/1 would never exceed 1
    float f = __uint_as_float(v);
    if (!(f == 0.0f || f == 1.0f)) bf = 1;  // float 0.0/1.0 pattern
  }
  if (bi) atomicOr(&bad_int, 1);
  if (bf) atomicOr(&bad_float, 1);
  __syncthreads();
  if (threadIdx.x == 0)
    *flag = (bad_int == 0) ? 0 : ((bad_float == 0) ? 1 : 2);  // 0=int32 1=f32 2=u8
}

// ---------------- kernel A: source = W @ context ----------------
// grid (8, 32): i-tile of 32 x full L=128 per block. 256 threads, acc[4][4].
__global__ __launch_bounds__(256) void proj_kernel(const float* __restrict__ W,
                                                   const float* __restrict__ ctx,
                                                   float* __restrict__ src) {
  __shared__ float sWt[16][33];   // [c][i] transposed, +1 pad
  __shared__ float sC[16 * NL];   // [c][l]
  const int tid = threadIdx.x;
  const int b = blockIdx.y;
  const int i0 = blockIdx.x * 32;
  const int tx = tid & 31;   // l quad: l = tx*4+jl
  const int ty = tid >> 5;   // i group: i = ty*4+ii
  float acc[4][4] = {};
  const float* ctxb = ctx + (size_t)b * CDF * NL;
  for (int c0 = 0; c0 < CDF; c0 += 16) {
    if (tid < 128) {
      int i = tid >> 2, cq = tid & 3;
      float4 w4 = *(const float4*)(W + (size_t)(i0 + i) * CDF + c0 + cq * 4);
      sWt[cq * 4 + 0][i] = w4.x; sWt[cq * 4 + 1][i] = w4.y;
      sWt[cq * 4 + 2][i] = w4.z; sWt[cq * 4 + 3][i] = w4.w;
    }
#pragma unroll
    for (int k = 0; k < 2; ++k) {
      int idx = tid + k * 256;
      int r = idx >> 5, c4 = idx & 31;
      *(float4*)(sC + r * NL + c4 * 4) =
          *(const float4*)(ctxb + (size_t)(c0 + r) * NL + c4 * 4);
    }
    __syncthreads();
#pragma unroll
    for (int cc = 0; cc < 16; ++cc) {
      float4 c4 = *(const float4*)(sC + cc * NL + tx * 4);
#pragma unroll
      for (int ii = 0; ii < 4; ++ii) {
        float w = sWt[cc][ty * 4 + ii];
        acc[ii][0] = fmaf(w, c4.x, acc[ii][0]);
        acc[ii][1] = fmaf(w, c4.y, acc[ii][1]);
        acc[ii][2] = fmaf(w, c4.z, acc[ii][2]);
        acc[ii][3] = fmaf(w, c4.w, acc[ii][3]);
      }
    }
    __syncthreads();
  }
  float* sp = src + (size_t)b * IDF * NL;
#pragma unroll
  for (int ii = 0; ii < 4; ++ii)
    *(float4*)(sp + (size_t)(i0 + ty * 4 + ii) * NL + tx * 4) =
        make_float4(acc[ii][0], acc[ii][1], acc[ii][2], acc[ii][3]);
}

// ---------------- kernel B: fused logits -> softmax -> attn out -> PV ----------------
// grid (64, 32): one (batch, 64-p tile) per block, 256 threads.
__global__ __launch_bounds__(256) void attn_kernel(
    const float* __restrict__ x, const float* __restrict__ src,
    const void* __restrict__ maskp, const int* __restrict__ flagp,
    float* __restrict__ out0, float* __restrict__ out1) {
  __shared__ float sA[64][129];  // attn [p][l] padded   (33 KB)
  __shared__ float sB[4352];     // phase1: sX[16][64]+sS[16][128]; phase4: bf16 [64][136] (17 KB)
  const int tid = threadIdx.x;
  const int b = blockIdx.y;
  const int p0 = blockIdx.x * 64;
  const int tx = tid & 31;  // l quad
  const int ty = tid >> 5;  // p group of 8

  // --- mask bits: reference tiles mask so row used = p % 32 (b-independent) ---
  const int mode = *flagp;
  unsigned int mbits = 0u;
#pragma unroll
  for (int pp = 0; pp < 8; ++pp) {
    int mrow = (ty * 8 + pp) & 31;  // p0 % 32 == 0 always
#pragma unroll
    for (int jl = 0; jl < 4; ++jl) {
      int idx = mrow * NL + tx * 4 + jl;
      int mv;
      if (mode == 0)      mv = ((const int*)maskp)[idx] != 0;
      else if (mode == 1) mv = ((const float*)maskp)[idx] != 0.0f;
      else                mv = ((const unsigned char*)maskp)[idx] != 0;
      mbits |= (unsigned)mv << (pp * 4 + jl);
    }
  }

  // --- phase 1: logits[64p][128l] = sum_i x[i][p] * src[i][l] (fp32, exact path) ---
  float acc[8][4] = {};
  float* sX = sB;         // [16][64]
  float* sS = sB + 1024;  // [16][128]
  const float* xb = x + (size_t)b * IDF * HXW + p0;
  const float* sb = src + (size_t)b * IDF * NL;
  for (int c0 = 0; c0 < IDF; c0 += 16) {
    {
      int ii = tid >> 4, pq = tid & 15;
      *(float4*)(sX + ii * 64 + pq * 4) =
          *(const float4*)(xb + (size_t)(c0 + ii) * HXW + pq * 4);
    }
#pragma unroll
    for (int k = 0; k < 2; ++k) {
      int idx = tid + k * 256;
      int r = idx >> 5, c4 = idx & 31;
      *(float4*)(sS + r * NL + c4 * 4) =
          *(const float4*)(sb + (size_t)(c0 + r) * NL + c4 * 4);
    }
    __syncthreads();
#pragma unroll
    for (int cc = 0; cc < 16; ++cc) {
      float4 s4 = *(const float4*)(sS + cc * NL + tx * 4);
      float4 xa = *(const float4*)(sX + cc * 64 + ty * 8);
      float4 xc = *(const float4*)(sX + cc * 64 + ty * 8 + 4);
      float xsv[8] = {xa.x, xa.y, xa.z, xa.w, xc.x, xc.y, xc.z, xc.w};
#pragma unroll
      for (int pp = 0; pp < 8; ++pp) {
        acc[pp][0] = fmaf(xsv[pp], s4.x, acc[pp][0]);
        acc[pp][1] = fmaf(xsv[pp], s4.y, acc[pp][1]);
        acc[pp][2] = fmaf(xsv[pp], s4.z, acc[pp][2]);
        acc[pp][3] = fmaf(xsv[pp], s4.w, acc[pp][3]);
      }
    }
    __syncthreads();
  }

  // --- phase 2: masked softmax per p row (row = 32 lanes of same ty) ---
#pragma unroll
  for (int pp = 0; pp < 8; ++pp) {
    float m = -3.0e38f;
#pragma unroll
    for (int jl = 0; jl < 4; ++jl) {
      if ((mbits >> (pp * 4 + jl)) & 1u) acc[pp][jl] = -3.0e38f;
      m = fmaxf(m, acc[pp][jl]);
    }
#pragma unroll
    for (int d = 16; d >= 1; d >>= 1) m = fmaxf(m, __shfl_xor(m, d, 64));
    float s = 0.0f;
#pragma unroll
    for (int jl = 0; jl < 4; ++jl) {
      float e = __expf(acc[pp][jl] - m);  // masked: exp(-huge) -> 0
      acc[pp][jl] = e;
      s += e;
    }
#pragma unroll
    for (int d = 16; d >= 1; d >>= 1) s += __shfl_xor(s, d, 64);
    float inv = 1.0f / s;
#pragma unroll
    for (int jl = 0; jl < 4; ++jl) acc[pp][jl] *= inv;
  }

  // --- phase 3: stage attn to LDS, write out1[b][l][p] coalesced ---
#pragma unroll
  for (int pp = 0; pp < 8; ++pp)
#pragma unroll
    for (int jl = 0; jl < 4; ++jl)
      sA[ty * 8 + pp][tx * 4 + jl] = acc[pp][jl];
  __syncthreads();
  float* o1 = out1 + (size_t)b * NL * HXW + p0;
#pragma unroll
  for (int k = 0; k < 8; ++k) {
    int idx = tid + k * 256;
    int l = idx >> 4, pq = idx & 15;
    float4 v = make_float4(sA[pq * 4 + 0][l], sA[pq * 4 + 1][l],
                           sA[pq * 4 + 2][l], sA[pq * 4 + 3][l]);
    *(float4*)(o1 + (size_t)l * HXW + pq * 4) = v;
  }

  // --- phase 4: result[i][p] = sum_l src[i][l]*attn[p][l]; src staged bf16 (err << thr) ---
  const int txp = tid & 15;  // p quad
  const int ti = tid >> 4;   // i group of 4
  unsigned short* sSb = (unsigned short*)sB;  // [64][136] bf16
  float* o0 = out0 + (size_t)b * IDF * HXW + p0;
  for (int it = 0; it < 4; ++it) {
    __syncthreads();  // protect sB from previous phase's readers
    const float* s0 = sb + (size_t)it * 64 * NL;
#pragma unroll
    for (int k = 0; k < 8; ++k) {
      int idx = tid + k * 256;  // float4 index 0..2047
      int r = idx >> 5, c4 = idx & 31;
      float4 v = *(const float4*)(s0 + (size_t)r * NL + c4 * 4);
      ushort4 h;
      h.x = f2bf(v.x); h.y = f2bf(v.y); h.z = f2bf(v.z); h.w = f2bf(v.w);
      *(ushort4*)(sSb + r * 136 + c4 * 4) = h;
    }
    __syncthreads();
    float racc[4][4] = {};
#pragma unroll 4
    for (int l = 0; l < NL; ++l) {
      float a0 = sA[txp * 4 + 0][l], a1 = sA[txp * 4 + 1][l];
      float a2 = sA[txp * 4 + 2][l], a3 = sA[txp * 4 + 3][l];
#pragma unroll
      for (int ii = 0; ii < 4; ++ii) {
        float sv = __uint_as_float((unsigned)sSb[(ti * 4 + ii) * 136 + l] << 16);
        racc[ii][0] = fmaf(sv, a0, racc[ii][0]);
        racc[ii][1] = fmaf(sv, a1, racc[ii][1]);
        racc[ii][2] = fmaf(sv, a2, racc[ii][2]);
        racc[ii][3] = fmaf(sv, a3, racc[ii][3]);
      }
    }
#pragma unroll
    for (int ii = 0; ii < 4; ++ii)
      *(float4*)(o0 + (size_t)(it * 64 + ti * 4 + ii) * HXW + txp * 4) =
          make_float4(racc[ii][0], racc[ii][1], racc[ii][2], racc[ii][3]);
  }
}

extern "C" void kernel_launch(void* const* d_in, const int* in_sizes, int n_in,
                              void* d_out, int out_size, void* d_ws, size_t ws_size,
                              hipStream_t stream) {
  const float* x   = (const float*)d_in[0];
  const float* ctx = (const float*)d_in[1];
  const float* W   = (const float*)d_in[2];
  const void*  msk = d_in[3];
  float* out0 = (float*)d_out;                       // [32][256][64][64]
  float* out1 = out0 + (size_t)NB * IDF * HXW;       // [32][128][64][64]
  int*   flag = (int*)d_ws;
  float* src  = (float*)((char*)d_ws + 1024);        // [32][256][128]

  detect_mask_kernel<<<1, 256, 0, stream>>>((const unsigned int*)msk, flag);
  proj_kernel<<<dim3(8, NB), 256, 0, stream>>>(W, ctx, src);
  attn_kernel<<<dim3(HXW / 64, NB), 256, 0, stream>>>(x, src, msk, flag, out0, out1);
}

// Round 2
// 131.948 us; speedup vs baseline: 3.8026x; 3.8026x over previous
//
#include <hip/hip_runtime.h>
#include <cstdint>

#define IDF 256
#define CDF 256
#define NL  128
#define HXW 4096
#define NB  32
#define PTILE 64

typedef _Float16 f16x8 __attribute__((ext_vector_type(8)));
typedef float f32x4 __attribute__((ext_vector_type(4)));
typedef unsigned short u16;
typedef unsigned int u32;

union Frag { f16x8 v; u32 u[4]; uint2 u2[2]; };

__device__ __forceinline__ u16 f2h(float f) { union { _Float16 h; u16 s; } c; c.h = (_Float16)f; return c.s; }
__device__ __forceinline__ float h2f(u16 s) { union { _Float16 h; u16 s; } c; c.s = s; return (float)c.h; }
__device__ __forceinline__ u32 pk2(float a, float b) { return (u32)f2h(a) | ((u32)f2h(b) << 16); }

// ws layout (bytes): [0..3] mode flag; [256..767] packed mask bits (32 rows x 4 u32);
// [1024 ..] src_f16 [b][i][l] (2 MB); [1024+2MB ..] srcT_f16 [b][l][i] (2 MB). Total 4,195,328 B.

// ---------------- prep: mask dtype detection + bit packing ----------------
__global__ void prep_kernel(const u32* __restrict__ m, u32* __restrict__ ws0) {
  __shared__ int bi_s, bf_s, mode_s;
  if (threadIdx.x == 0) { bi_s = 0; bf_s = 0; }
  __syncthreads();
  int bi = 0, bfl = 0;
  for (int k = 0; k < 4; ++k) {
    u32 v = m[threadIdx.x * 4 + k];   // first 4KB: valid subset for i32/f32/u8
    if (v > 1u) bi = 1;               // int32 0/1 never exceeds 1
    float f = __uint_as_float(v);
    if (!(f == 0.0f || f == 1.0f)) bfl = 1;
  }
  if (bi) atomicOr(&bi_s, 1);
  if (bfl) atomicOr(&bf_s, 1);
  __syncthreads();
  if (threadIdx.x == 0) { mode_s = (bi_s == 0) ? 0 : ((bf_s == 0) ? 1 : 2); ws0[0] = (u32)mode_s; }
  __syncthreads();
  const int mode = mode_s;
  if (threadIdx.x < 128) {
    int row = threadIdx.x >> 2, q = threadIdx.x & 3;
    u32 bits = 0;
    for (int c = 0; c < 32; ++c) {
      int idx = row * NL + q * 32 + c;
      int mv;
      if (mode == 0)      mv = ((const int*)m)[idx] != 0;
      else if (mode == 1) mv = ((const float*)m)[idx] != 0.0f;
      else                mv = ((const unsigned char*)m)[idx] != 0;
      bits |= (u32)mv << c;
    }
    ws0[64 + row * 4 + q] = bits;   // byte offset 256
  }
}

// ---------------- proj: src = W @ ctx, emit fp16 in both layouts ----------------
__global__ __launch_bounds__(256) void proj_kernel(const float* __restrict__ W,
                                                   const float* __restrict__ ctx,
                                                   u16* __restrict__ srcF,
                                                   u16* __restrict__ srcT) {
  __shared__ float sWt[16][33];
  __shared__ float sC[16 * NL];
  const int tid = threadIdx.x;
  const int b = blockIdx.y;
  const int i0 = blockIdx.x * 32;
  const int tx = tid & 31;   // l quad
  const int ty = tid >> 5;   // i group of 4
  float acc[4][4] = {};
  const float* ctxb = ctx + (size_t)b * CDF * NL;
  for (int c0 = 0; c0 < CDF; c0 += 16) {
    if (tid < 128) {
      int i = tid >> 2, cq = tid & 3;
      float4 w4 = *(const float4*)(W + (size_t)(i0 + i) * CDF + c0 + cq * 4);
      sWt[cq * 4 + 0][i] = w4.x; sWt[cq * 4 + 1][i] = w4.y;
      sWt[cq * 4 + 2][i] = w4.z; sWt[cq * 4 + 3][i] = w4.w;
    }
#pragma unroll
    for (int k = 0; k < 2; ++k) {
      int idx = tid + k * 256;
      int r = idx >> 5, c4 = idx & 31;
      *(float4*)(sC + r * NL + c4 * 4) =
          *(const float4*)(ctxb + (size_t)(c0 + r) * NL + c4 * 4);
    }
    __syncthreads();
#pragma unroll
    for (int cc = 0; cc < 16; ++cc) {
      float4 c4 = *(const float4*)(sC + cc * NL + tx * 4);
#pragma unroll
      for (int ii = 0; ii < 4; ++ii) {
        float w = sWt[cc][ty * 4 + ii];
        acc[ii][0] = fmaf(w, c4.x, acc[ii][0]);
        acc[ii][1] = fmaf(w, c4.y, acc[ii][1]);
        acc[ii][2] = fmaf(w, c4.z, acc[ii][2]);
        acc[ii][3] = fmaf(w, c4.w, acc[ii][3]);
      }
    }
    __syncthreads();
  }
  u16* sf = srcF + (size_t)b * IDF * NL;
  u16* st = srcT + (size_t)b * NL * IDF;
#pragma unroll
  for (int ii = 0; ii < 4; ++ii) {
    int i = i0 + ty * 4 + ii;
    u32 d0 = pk2(acc[ii][0], acc[ii][1]);
    u32 d1 = pk2(acc[ii][2], acc[ii][3]);
    *(uint2*)(sf + (size_t)i * NL + tx * 4) = make_uint2(d0, d1);
#pragma unroll
    for (int jl = 0; jl < 4; ++jl)
      st[(size_t)(tx * 4 + jl) * IDF + i] = f2h(acc[ii][jl]);
  }
}

// ---------------- fused attention: QK^T (MFMA) -> softmax -> out1 -> PV (MFMA) -> out0 ----
__global__ __launch_bounds__(256) void attn_kernel(
    const float* __restrict__ x, const u16* __restrict__ srcF,
    const u16* __restrict__ srcT, const u32* __restrict__ wsm,
    float* __restrict__ out0, float* __restrict__ out1) {
  __shared__ __align__(16) u16 sA[64 * 132];    // attn fp16 [p][l], stride 132
  __shared__ __align__(16) u16 sXT[64 * 44];    // x^T fp16 [p][k], stride 44 (packed k-pairs)
  __shared__ __align__(16) u16 sST[128 * 44];   // srcT chunk fp16 [l][k], stride 44

  const int tid = threadIdx.x;
  const int lane = tid & 63;
  const int w = tid >> 6;        // wave 0..3
  const int m15 = lane & 15;
  const int g = lane >> 4;       // 0..3
  const int b = blockIdx.y;
  const int p0 = blockIdx.x * PTILE;

  // ---- phase 1: QK^T logits[64p][128l], K=256 in chunks of 32 ----
  f32x4 accq[8];
#pragma unroll
  for (int nt = 0; nt < 8; ++nt) accq[nt] = f32x4{0.f, 0.f, 0.f, 0.f};

  const float* xb = x + (size_t)b * IDF * HXW + p0;
  const u16* stb = srcT + (size_t)b * NL * IDF;
  const int kp = tid >> 4;         // 0..15: k-pair (rows 2kp, 2kp+1)
  const int p4 = (tid & 15) * 4;   // p quad
  const int sl = tid >> 1;         // 0..127: srcT row
  const int sh = tid & 1;          // half of 32-element row

  u32* xd = (u32*)sXT;
  u32* sd = (u32*)sST;

  for (int ic = 0; ic < 8; ++ic) {
    const float* xp = xb + (size_t)(ic * 32 + kp * 2) * HXW + p4;
    float4 xa = *(const float4*)xp;
    float4 xc = *(const float4*)(xp + HXW);
    const u16* sp = stb + (size_t)sl * IDF + ic * 32 + sh * 16;
    uint4 s0 = *(const uint4*)sp;
    uint4 s1 = *(const uint4*)(sp + 8);
    // transposed x write: dword (p*22 + kp) holds k = 2kp (lo), 2kp+1 (hi)
    xd[(p4 + 0) * 22 + kp] = pk2(xa.x, xc.x);
    xd[(p4 + 1) * 22 + kp] = pk2(xa.y, xc.y);
    xd[(p4 + 2) * 22 + kp] = pk2(xa.z, xc.z);
    xd[(p4 + 3) * 22 + kp] = pk2(xa.w, xc.w);
    int sb0 = sl * 22 + sh * 8;
    *(uint2*)(sd + sb0 + 0) = make_uint2(s0.x, s0.y);
    *(uint2*)(sd + sb0 + 2) = make_uint2(s0.z, s0.w);
    *(uint2*)(sd + sb0 + 4) = make_uint2(s1.x, s1.y);
    *(uint2*)(sd + sb0 + 6) = make_uint2(s1.z, s1.w);
    __syncthreads();
    Frag af;
    {
      const u32* xr = (const u32*)sXT + (w * 16 + m15) * 22 + g * 4;
      af.u2[0] = *(const uint2*)xr;
      af.u2[1] = *(const uint2*)(xr + 2);
    }
#pragma unroll
    for (int nt = 0; nt < 8; ++nt) {
      Frag bf;
      const u32* br = (const u32*)sST + (nt * 16 + m15) * 22 + g * 4;
      bf.u2[0] = *(const uint2*)br;
      bf.u2[1] = *(const uint2*)(br + 2);
      accq[nt] = __builtin_amdgcn_mfma_f32_16x16x32_f16(af.v, bf.v, accq[nt], 0, 0, 0);
    }
    __syncthreads();
  }

  // ---- phase 2: masked softmax (rows spread over 16-lane groups) ----
  const int prow = w * 16 + g * 4;  // + r
#pragma unroll
  for (int r = 0; r < 4; ++r) {
    int rm = (prow + r) & 31;       // mask row = p % 32 (p0 multiple of 64)
    uint4 mr = *(const uint4*)(wsm + rm * 4);
    u32 mw[4] = {mr.x, mr.y, mr.z, mr.w};
    float mx = -3.0e38f;
#pragma unroll
    for (int nt = 0; nt < 8; ++nt) {
      u32 bits = mw[nt >> 1] >> ((nt & 1) * 16);
      if ((bits >> m15) & 1u) accq[nt][r] = -3.0e38f;
      mx = fmaxf(mx, accq[nt][r]);
    }
    mx = fmaxf(mx, __shfl_xor(mx, 1));
    mx = fmaxf(mx, __shfl_xor(mx, 2));
    mx = fmaxf(mx, __shfl_xor(mx, 4));
    mx = fmaxf(mx, __shfl_xor(mx, 8));
    float e[8];
    float s = 0.f;
#pragma unroll
    for (int nt = 0; nt < 8; ++nt) { e[nt] = __expf(accq[nt][r] - mx); s += e[nt]; }
    s += __shfl_xor(s, 1); s += __shfl_xor(s, 2);
    s += __shfl_xor(s, 4); s += __shfl_xor(s, 8);
    float inv = 1.0f / s;
#pragma unroll
    for (int nt = 0; nt < 8; ++nt)
      sA[(prow + r) * 132 + nt * 16 + m15] = f2h(e[nt] * inv);
  }
  __syncthreads();

  // ---- phase 3: out1[b][l][p] from sA (transpose read) ----
  float* o1 = out1 + (size_t)b * NL * HXW + p0;
  const int po = (tid & 7) * 8;
  const int lb = tid >> 3;  // 0..31
#pragma unroll
  for (int pass = 0; pass < 4; ++pass) {
    int l = pass * 32 + lb;
    float4 v0, v1;
    v0.x = h2f(sA[(po + 0) * 132 + l]); v0.y = h2f(sA[(po + 1) * 132 + l]);
    v0.z = h2f(sA[(po + 2) * 132 + l]); v0.w = h2f(sA[(po + 3) * 132 + l]);
    v1.x = h2f(sA[(po + 4) * 132 + l]); v1.y = h2f(sA[(po + 5) * 132 + l]);
    v1.z = h2f(sA[(po + 6) * 132 + l]); v1.w = h2f(sA[(po + 7) * 132 + l]);
    *(float4*)(o1 + (size_t)l * HXW + po) = v0;
    *(float4*)(o1 + (size_t)l * HXW + po + 4) = v1;
  }

  // ---- phase 4: PV — out0[i][p] = mfma(src[i][l], attn[p][l]), per wave 64 i ----
  f32x4 accp[4][4];
#pragma unroll
  for (int mt = 0; mt < 4; ++mt)
#pragma unroll
    for (int nt2 = 0; nt2 < 4; ++nt2) accp[mt][nt2] = f32x4{0.f, 0.f, 0.f, 0.f};

  const u16* sfb = srcF + (size_t)b * IDF * NL;
  const u32* sAd = (const u32*)sA;
#pragma unroll
  for (int ks = 0; ks < 4; ++ks) {
    Frag af[4], bf[4];
#pragma unroll
    for (int mt = 0; mt < 4; ++mt) {
      int row = w * 64 + mt * 16 + m15;
      uint4 t = *(const uint4*)(sfb + (size_t)row * NL + ks * 32 + g * 8);
      af[mt].u[0] = t.x; af[mt].u[1] = t.y; af[mt].u[2] = t.z; af[mt].u[3] = t.w;
    }
#pragma unroll
    for (int nt2 = 0; nt2 < 4; ++nt2) {
      int di = (nt2 * 16 + m15) * 66 + ks * 16 + g * 4;
      bf[nt2].u2[0] = *(const uint2*)(sAd + di);
      bf[nt2].u2[1] = *(const uint2*)(sAd + di + 2);
    }
#pragma unroll
    for (int mt = 0; mt < 4; ++mt)
#pragma unroll
      for (int nt2 = 0; nt2 < 4; ++nt2)
        accp[mt][nt2] = __builtin_amdgcn_mfma_f32_16x16x32_f16(af[mt].v, bf[nt2].v, accp[mt][nt2], 0, 0, 0);
  }

  float* o0 = out0 + (size_t)b * IDF * HXW + p0;
#pragma unroll
  for (int mt = 0; mt < 4; ++mt)
#pragma unroll
    for (int nt2 = 0; nt2 < 4; ++nt2) {
      int col = nt2 * 16 + m15;
#pragma unroll
      for (int r = 0; r < 4; ++r) {
        int row = w * 64 + mt * 16 + g * 4 + r;
        o0[(size_t)row * HXW + col] = accp[mt][nt2][r];
      }
    }
}

extern "C" void kernel_launch(void* const* d_in, const int* in_sizes, int n_in,
                              void* d_out, int out_size, void* d_ws, size_t ws_size,
                              hipStream_t stream) {
  const float* x   = (const float*)d_in[0];
  const float* ctx = (const float*)d_in[1];
  const float* W   = (const float*)d_in[2];
  const void*  msk = d_in[3];
  float* out0 = (float*)d_out;                       // [32][256][64][64]
  float* out1 = out0 + (size_t)NB * IDF * HXW;       // [32][128][64][64]
  u32* ws0 = (u32*)d_ws;
  u16* srcF = (u16*)((char*)d_ws + 1024);            // [32][256][128] f16
  u16* srcT = (u16*)((char*)d_ws + 1024 + 2097152);  // [32][128][256] f16

  prep_kernel<<<1, 256, 0, stream>>>((const u32*)msk, ws0);
  proj_kernel<<<dim3(8, NB), 256, 0, stream>>>(W, ctx, srcF, srcT);
  attn_kernel<<<dim3(HXW / PTILE, NB), 256, 0, stream>>>(x, srcF, srcT, ws0 + 64, out0, out1);
}